// Round 3
// baseline (4863.285 us; speedup 1.0000x reference)
//
#include <hip/hip_runtime.h>

typedef short short8 __attribute__((ext_vector_type(8)));
typedef float f4 __attribute__((ext_vector_type(4)));
typedef _Float16 half8 __attribute__((ext_vector_type(8)));
typedef _Float16 h2 __attribute__((ext_vector_type(2)));

#define HD 256
#define ED 300
#define EP 320
#define TH 768
#define NS 1024
#define LW 64

__device__ __forceinline__ unsigned short f2bf(float f) {
    unsigned int u = __float_as_uint(f);
    u = (u + 0x7FFFu + ((u >> 16) & 1u)) >> 16;
    return (unsigned short)u;
}
__device__ __forceinline__ float bf2f(unsigned short s) {
    return __uint_as_float(((unsigned int)s) << 16);
}
__device__ __forceinline__ float sigm(float x) {
    return __builtin_amdgcn_rcpf(1.f + __expf(-x));
}
__device__ __forceinline__ float tanh_(float x) {
    x = fminf(fmaxf(x, -15.f), 15.f);
    return 1.f - 2.f * __builtin_amdgcn_rcpf(1.f + __expf(2.f * x));
}
__device__ __forceinline__ unsigned int pack_h2(float a, float b) {
    h2 p; p.x = (_Float16)a; p.y = (_Float16)b;
    return __builtin_bit_cast(unsigned int, p);
}

__device__ __forceinline__ void load8bf(const unsigned short* p, float* o) {
    uint4 a = *(const uint4*)p;
    o[0] = bf2f((unsigned short)(a.x & 0xffff)); o[1] = bf2f((unsigned short)(a.x >> 16));
    o[2] = bf2f((unsigned short)(a.y & 0xffff)); o[3] = bf2f((unsigned short)(a.y >> 16));
    o[4] = bf2f((unsigned short)(a.z & 0xffff)); o[5] = bf2f((unsigned short)(a.z >> 16));
    o[6] = bf2f((unsigned short)(a.w & 0xffff)); o[7] = bf2f((unsigned short)(a.w >> 16));
}
__device__ __forceinline__ void load4bf(const unsigned short* p, float* o) {
    uint2 a = *(const uint2*)p;
    o[0] = bf2f((unsigned short)(a.x & 0xffff)); o[1] = bf2f((unsigned short)(a.x >> 16));
    o[2] = bf2f((unsigned short)(a.y & 0xffff)); o[3] = bf2f((unsigned short)(a.y >> 16));
}

// ---------------- prep: weight conversions, Dq table, topic vector ----------------
__global__ void k_prep(const float* __restrict__ W, const float* __restrict__ U,
                       const float* __restrict__ Wih, const float* __restrict__ Whh,
                       const float* __restrict__ q, const float* __restrict__ Dm,
                       const float* __restrict__ DT, const float* __restrict__ mlpW,
                       const float* __restrict__ mlpb,
                       unsigned short* __restrict__ Wb, _Float16* __restrict__ Uh,
                       _Float16* __restrict__ Wihh, _Float16* __restrict__ Whhh,
                       float* __restrict__ Dq, float* __restrict__ tv) {
    int bid = blockIdx.x, tid = threadIdx.x;
    if (bid < 768) {
        int r = bid;
        for (int j = tid; j < EP; j += 256)
            Wb[r * EP + j] = (j < ED) ? f2bf(W[r * ED + j]) : (unsigned short)0;
        for (int j = tid; j < HD; j += 256) {
            Uh[r * HD + j] = (_Float16)U[r * HD + j];
            Wihh[r * HD + j] = (_Float16)Wih[r * HD + j];
            Whhh[r * HD + j] = (_Float16)Whh[r * HD + j];
        }
    } else if (bid < 798) {
        int idx = bid - 768;
        int d = idx / 3, part = idx - d * 3;
        int n = part * 256 + tid;
        float s = 0.f;
        for (int h = 0; h < HD; ++h) s += Dm[n * HD + h] * q[d * HD + h];
        Dq[d * TH + n] = s;
    } else {
        if (tid < HD) {
            float s = 0.f;
            for (int k = 0; k < 100; ++k) s += mlpW[tid * 100 + k] * DT[k];
            tv[tid] = tanh_(s + mlpb[tid]);
        }
    }
}

// ---------------- phase B: pre[m][n] = (x @ W^T)[m][n] + Dq_table[dep(m)][n] + b[n] ----------------
__launch_bounds__(256, 2)
__global__ void k_phaseB(const int* __restrict__ sIdx, const int* __restrict__ depT,
                         const float* __restrict__ emb, const unsigned short* __restrict__ Wb,
                         const float* __restrict__ Dq, const float* __restrict__ bias,
                         unsigned short* __restrict__ pre) {
    __shared__ float dq_s[10 * 772];
    __shared__ float b_s[TH];
    __shared__ int dep_s[32];
    __shared__ int idx_s[32];
    int tid = threadIdx.x;
    int c0 = blockIdx.x * 32;
    for (int i = tid; i < 10 * 768; i += 256) {
        int d = i / 768, n = i - d * 768;
        dq_s[d * 772 + n] = Dq[i];
    }
    for (int i = tid; i < TH; i += 256) b_s[i] = bias[i];
    if (tid < 32) {
        int m = c0 + tid;
        idx_s[tid] = sIdx[m];
        int l = m & 63, s = m >> 6;
        dep_s[tid] = (l == 63) ? 9 : depT[s * 63 + l];
    }
    __syncthreads();

    int lane = tid & 63;
    int w = tid >> 6;
    int quad = lane >> 4, l16 = lane & 15;

    const float* xr0 = emb + (long)idx_s[l16] * ED;
    const float* xr1 = emb + (long)idx_s[16 + l16] * ED;

    f4 acc[2][12];
#pragma unroll
    for (int cs = 0; cs < 2; ++cs)
#pragma unroll
        for (int ms = 0; ms < 12; ++ms) acc[cs][ms] = (f4){0.f, 0.f, 0.f, 0.f};

    const unsigned short* wbase = Wb + (w * 192 + l16) * EP;

#pragma unroll
    for (int kt = 0; kt < 10; ++kt) {
        int k0 = kt * 32 + quad * 8;
        short8 bf[2];
#pragma unroll
        for (int cs = 0; cs < 2; ++cs) {
            const float* xr = cs ? xr1 : xr0;
            float xv[8];
            if (k0 + 8 <= ED) {
                float4 f0 = *(const float4*)(xr + k0);
                float4 f1 = *(const float4*)(xr + k0 + 4);
                xv[0] = f0.x; xv[1] = f0.y; xv[2] = f0.z; xv[3] = f0.w;
                xv[4] = f1.x; xv[5] = f1.y; xv[6] = f1.z; xv[7] = f1.w;
            } else {
#pragma unroll
                for (int j = 0; j < 8; ++j) xv[j] = (k0 + j < ED) ? xr[k0 + j] : 0.f;
            }
            short8 t;
#pragma unroll
            for (int j = 0; j < 8; ++j) t[j] = (short)f2bf(xv[j]);
            bf[cs] = t;
        }
#pragma unroll
        for (int ms = 0; ms < 12; ++ms) {
            short8 af = *(const short8*)(wbase + ms * 16 * EP + k0);
            acc[0][ms] = __builtin_amdgcn_mfma_f32_16x16x32_bf16(af, bf[0], acc[0][ms], 0, 0, 0);
            acc[1][ms] = __builtin_amdgcn_mfma_f32_16x16x32_bf16(af, bf[1], acc[1][ms], 0, 0, 0);
        }
    }

#pragma unroll
    for (int cs = 0; cs < 2; ++cs) {
        int xr = c0 + cs * 16 + l16;
        int dep = dep_s[cs * 16 + l16];
        unsigned short* prow = pre + (long)xr * TH;
#pragma unroll
        for (int ms = 0; ms < 12; ++ms) {
            int ncol = w * 192 + ms * 16 + quad * 4;
            f4 dq4 = *(const f4*)&dq_s[dep * 772 + ncol];
            f4 b4 = *(const f4*)&b_s[ncol];
            unsigned int lo = (unsigned int)f2bf(acc[cs][ms][0] + dq4[0] + b4[0]) |
                              ((unsigned int)f2bf(acc[cs][ms][1] + dq4[1] + b4[1]) << 16);
            unsigned int hi = (unsigned int)f2bf(acc[cs][ms][2] + dq4[2] + b4[2]) |
                              ((unsigned int)f2bf(acc[cs][ms][3] + dq4[3] + b4[3]) << 16);
            uint2 v; v.x = lo; v.y = hi;
            *(uint2*)(prow + ncol) = v;
        }
    }
}

// ---------------- phase C v3: U register-resident (launch_bounds fixed), 16 sentences/WG ----------------
__launch_bounds__(768, 3)
__global__ void k_phaseC(const unsigned short* __restrict__ pre,
                         const _Float16* __restrict__ Uh,
                         const _Float16* __restrict__ Wihh,
                         const float* __restrict__ bih,
                         float* __restrict__ gi) {
    __shared__ __align__(16) uint4 hfr[512];        // [kt][lane] B-fragments of h
    __shared__ __align__(16) float tot[16 * 772];   // [sentence][row] (padded)
    int tid = threadIdx.x;
    int lane = tid & 63, w = tid >> 6, quad = lane >> 4, l16 = lane & 15;
    int s0 = blockIdx.x * 16;

    uint4 frag[32];
    {
        const _Float16* base = Uh + (w * 64 + l16) * HD;
#pragma unroll
        for (int t = 0; t < 4; ++t)
#pragma unroll
            for (int kt = 0; kt < 8; ++kt)
                frag[t * 8 + kt] = *(const uint4*)(base + t * 16 * HD + kt * 32 + quad * 8);
    }

    int us = tid >> 5;           // sentence (tid<512)
    int jg = tid & 31;
    int j0 = jg * 8;
    int hcell = (j0 >> 5) * 64 + 16 * ((j0 >> 3) & 3) + us;
    uint4 hcp;                    // this thread's 8 h values, packed f16x2

    if (tid < 512) {
        const unsigned short* prow = pre + ((long)(s0 + us) * LW + 63) * TH;
        float iv[8], uv[8], hcv[8];
        load8bf(prow + 256 + j0, iv);
        load8bf(prow + 512 + j0, uv);
#pragma unroll
        for (int r = 0; r < 8; ++r) hcv[r] = tanh_(sigm(iv[r]) * tanh_(uv[r]));
        hcp.x = pack_h2(hcv[0], hcv[1]); hcp.y = pack_h2(hcv[2], hcv[3]);
        hcp.z = pack_h2(hcv[4], hcv[5]); hcp.w = pack_h2(hcv[6], hcv[7]);
        hfr[hcell] = hcp;
    }
    __syncthreads();

    int mb = w * 64 + quad * 4;

    for (int step = 0; step < 63; ++step) {
        int l = 62 - step;
        f4 a0 = (f4){0,0,0,0}, a1 = (f4){0,0,0,0}, a2 = (f4){0,0,0,0}, a3 = (f4){0,0,0,0};
#pragma unroll
        for (int kt = 0; kt < 8; ++kt) {
            half8 b = __builtin_bit_cast(half8, hfr[kt * 64 + lane]);
            a0 = __builtin_amdgcn_mfma_f32_16x16x32_f16(__builtin_bit_cast(half8, frag[kt]), b, a0, 0, 0, 0);
            a1 = __builtin_amdgcn_mfma_f32_16x16x32_f16(__builtin_bit_cast(half8, frag[8 + kt]), b, a1, 0, 0, 0);
            a2 = __builtin_amdgcn_mfma_f32_16x16x32_f16(__builtin_bit_cast(half8, frag[16 + kt]), b, a2, 0, 0, 0);
            a3 = __builtin_amdgcn_mfma_f32_16x16x32_f16(__builtin_bit_cast(half8, frag[24 + kt]), b, a3, 0, 0, 0);
        }
        float* tr = tot + l16 * 772;
        *(f4*)&tr[mb] = a0;
        *(f4*)&tr[mb + 16] = a1;
        *(f4*)&tr[mb + 32] = a2;
        *(f4*)&tr[mb + 48] = a3;
        __syncthreads();
        if (tid < 512) {
            const unsigned short* prow = pre + ((long)(s0 + us) * LW + l) * TH;
            const float* ts = tot + us * 772;
            float hcv[8];
            h2 px = __builtin_bit_cast(h2, hcp.x); h2 py = __builtin_bit_cast(h2, hcp.y);
            h2 pz = __builtin_bit_cast(h2, hcp.z); h2 pw = __builtin_bit_cast(h2, hcp.w);
            hcv[0] = (float)px.x; hcv[1] = (float)px.y; hcv[2] = (float)py.x; hcv[3] = (float)py.y;
            hcv[4] = (float)pz.x; hcv[5] = (float)pz.y; hcv[6] = (float)pw.x; hcv[7] = (float)pw.y;
#pragma unroll
            for (int hf = 0; hf < 2; ++hf) {
                int jb = j0 + hf * 4;
                float pf[4], pi_[4], pu[4];
                load4bf(prow + jb, pf);
                load4bf(prow + 256 + jb, pi_);
                load4bf(prow + 512 + jb, pu);
                f4 tf = *(const f4*)&ts[jb];
                f4 ti = *(const f4*)&ts[256 + jb];
                f4 tu = *(const f4*)&ts[512 + jb];
#pragma unroll
                for (int r = 0; r < 4; ++r) {
                    float ff = tf[r] + pf[r];
                    float ii = ti[r] + pi_[r];
                    float uu = tu[r] + pu[r];
                    hcv[hf * 4 + r] = tanh_(sigm(ii) * tanh_(uu) + sigm(ff) * hcv[hf * 4 + r]);
                }
            }
            hcp.x = pack_h2(hcv[0], hcv[1]); hcp.y = pack_h2(hcv[2], hcv[3]);
            hcp.z = pack_h2(hcv[4], hcv[5]); hcp.w = pack_h2(hcv[6], hcv[7]);
            hfr[hcell] = hcp;
        }
        __syncthreads();
    }

    // epilogue: gi[s] = Wih @ sv_s + bih, reuse frag regs for Wih
    {
        const _Float16* base = Wihh + (w * 64 + l16) * HD;
#pragma unroll
        for (int t = 0; t < 4; ++t)
#pragma unroll
            for (int kt = 0; kt < 8; ++kt)
                frag[t * 8 + kt] = *(const uint4*)(base + t * 16 * HD + kt * 32 + quad * 8);
    }
    f4 a0 = (f4){0,0,0,0}, a1 = (f4){0,0,0,0}, a2 = (f4){0,0,0,0}, a3 = (f4){0,0,0,0};
#pragma unroll
    for (int kt = 0; kt < 8; ++kt) {
        half8 b = __builtin_bit_cast(half8, hfr[kt * 64 + lane]);
        a0 = __builtin_amdgcn_mfma_f32_16x16x32_f16(__builtin_bit_cast(half8, frag[kt]), b, a0, 0, 0, 0);
        a1 = __builtin_amdgcn_mfma_f32_16x16x32_f16(__builtin_bit_cast(half8, frag[8 + kt]), b, a1, 0, 0, 0);
        a2 = __builtin_amdgcn_mfma_f32_16x16x32_f16(__builtin_bit_cast(half8, frag[16 + kt]), b, a2, 0, 0, 0);
        a3 = __builtin_amdgcn_mfma_f32_16x16x32_f16(__builtin_bit_cast(half8, frag[24 + kt]), b, a3, 0, 0, 0);
    }
    float* go = gi + (long)(s0 + l16) * TH;
    f4 b0 = *(const f4*)(bih + mb);
    f4 b1 = *(const f4*)(bih + mb + 16);
    f4 b2 = *(const f4*)(bih + mb + 32);
    f4 b3 = *(const f4*)(bih + mb + 48);
    *(f4*)(go + mb) = a0 + b0;
    *(f4*)(go + mb + 16) = a1 + b1;
    *(f4*)(go + mb + 32) = a2 + b2;
    *(f4*)(go + mb + 48) = a3 + b3;
}

// ---------------- GRU v3: hybrid VALU(r,z rows) + MFMA(n rows), 1 WG, 1024 steps + head ----------------
__launch_bounds__(768, 3)
__global__ void k_gru(const _Float16* __restrict__ Whhh, const float* __restrict__ bhh,
                      const float* __restrict__ gi, const float* __restrict__ h0,
                      const float* __restrict__ tv,
                      const float* __restrict__ gateW, const float* __restrict__ gateU,
                      const float* __restrict__ gateb,
                      const float* __restrict__ outW, const float* __restrict__ outb,
                      float* __restrict__ out) {
    __shared__ __align__(16) _Float16 hb[HD];
    __shared__ __align__(16) float ghs[TH];
    __shared__ float hts[HD];
    __shared__ float sgs[512];
    __shared__ float vvs[HD];
    __shared__ float lg[8];

    int tid = threadIdx.x;
    int lane = tid & 63, w = tid >> 6, quad = lane >> 4, l16 = lane & 15;
    bool isV = (tid < 512);

    uint4 wv[32];   // VALU threads: own row of Whh (f16, 128 VGPRs)
    uint4 frag[32]; // MFMA waves: A-fragments for rows 512..767
    int rowbase = 512 + (w - 8) * 64;
    if (isV) {
        const uint4* wp = (const uint4*)(Whhh + (long)tid * HD);
#pragma unroll
        for (int i = 0; i < 32; ++i) wv[i] = wp[i];
    } else {
        const _Float16* base = Whhh + (long)(rowbase + l16) * HD;
#pragma unroll
        for (int t = 0; t < 4; ++t)
#pragma unroll
            for (int kt = 0; kt < 8; ++kt)
                frag[t * 8 + kt] = *(const uint4*)(base + t * 16 * HD + kt * 32 + quad * 8);
    }

    float br = 0.f, bz = 0.f, bn = 0.f, hj = 0.f;
    if (tid < HD) {
        hj = h0[tid];
        hb[tid] = (_Float16)hj;
        br = bhh[tid]; bz = bhh[256 + tid]; bn = bhh[512 + tid];
    }
    __syncthreads();

    for (int t = 0; t < NS; ++t) {
        float gr = 0.f, gz = 0.f, gn = 0.f;
        if (tid < HD) {
            const float* g = gi + (long)t * TH + tid;
            gr = g[0]; gz = g[256]; gn = g[512];
        }
        float rdot = 0.f;
        if (isV) {
            float a0 = 0.f, a1 = 0.f, a2 = 0.f, a3 = 0.f;
            const uint4* hp = (const uint4*)hb;
#pragma unroll
            for (int i = 0; i < 32; ++i) {
                uint4 hv = hp[i];
                a0 = __builtin_amdgcn_fdot2(__builtin_bit_cast(h2, wv[i].x), __builtin_bit_cast(h2, hv.x), a0, false);
                a1 = __builtin_amdgcn_fdot2(__builtin_bit_cast(h2, wv[i].y), __builtin_bit_cast(h2, hv.y), a1, false);
                a2 = __builtin_amdgcn_fdot2(__builtin_bit_cast(h2, wv[i].z), __builtin_bit_cast(h2, hv.z), a2, false);
                a3 = __builtin_amdgcn_fdot2(__builtin_bit_cast(h2, wv[i].w), __builtin_bit_cast(h2, hv.w), a3, false);
            }
            rdot = (a0 + a1) + (a2 + a3);
            if (tid >= 256) ghs[tid] = rdot;   // z rows publish; r rows keep in reg
        } else {
            f4 a0 = (f4){0,0,0,0}, a1 = (f4){0,0,0,0}, a2 = (f4){0,0,0,0}, a3 = (f4){0,0,0,0};
#pragma unroll
            for (int kt = 0; kt < 8; ++kt) {
                half8 b = __builtin_bit_cast(half8, *(const uint4*)&hb[kt * 32 + quad * 8]);
                a0 = __builtin_amdgcn_mfma_f32_16x16x32_f16(__builtin_bit_cast(half8, frag[kt]), b, a0, 0, 0, 0);
                a1 = __builtin_amdgcn_mfma_f32_16x16x32_f16(__builtin_bit_cast(half8, frag[8 + kt]), b, a1, 0, 0, 0);
                a2 = __builtin_amdgcn_mfma_f32_16x16x32_f16(__builtin_bit_cast(half8, frag[16 + kt]), b, a2, 0, 0, 0);
                a3 = __builtin_amdgcn_mfma_f32_16x16x32_f16(__builtin_bit_cast(half8, frag[24 + kt]), b, a3, 0, 0, 0);
            }
            if (l16 == 0) {
                int gb = rowbase + quad * 4;
                *(f4*)&ghs[gb] = a0;
                *(f4*)&ghs[gb + 16] = a1;
                *(f4*)&ghs[gb + 32] = a2;
                *(f4*)&ghs[gb + 48] = a3;
            }
        }
        __syncthreads();
        if (tid < HD) {
            float r = sigm(gr + rdot + br);
            float z = sigm(gz + ghs[256 + tid] + bz);
            float n = tanh_(gn + r * (ghs[512 + tid] + bn));
            hj = (1.f - z) * n + z * hj;
            hb[tid] = (_Float16)hj;
        }
        __syncthreads();
    }

    // head
    if (tid < HD) hts[tid] = hj;
    __syncthreads();
    if (tid < 512) {
        float s = gateb[tid];
        for (int k = 0; k < HD; ++k)
            s += gateW[tid * HD + k] * hts[k] + gateU[tid * HD + k] * tv[k];
        sgs[tid] = sigm(s);
    }
    __syncthreads();
    if (tid < HD) vvs[tid] = tanh_(sgs[tid] * hts[tid] + sgs[256 + tid] * tv[tid]);
    __syncthreads();
    if (tid < 5) {
        float s = outb[tid];
        for (int k = 0; k < HD; ++k) s += outW[tid * HD + k] * vvs[k];
        lg[tid] = s;
    }
    __syncthreads();
    if (tid == 0) {
        float m = lg[0];
        for (int i = 1; i < 5; ++i) m = fmaxf(m, lg[i]);
        float e[5], sum = 0.f;
        for (int i = 0; i < 5; ++i) { e[i] = __expf(lg[i] - m); sum += e[i]; }
        for (int i = 0; i < 5; ++i) out[i] = e[i] / sum;
    }
}

extern "C" void kernel_launch(void* const* d_in, const int* in_sizes, int n_in,
                              void* d_out, int out_size, void* d_ws, size_t ws_size,
                              hipStream_t stream) {
    (void)in_sizes; (void)n_in; (void)out_size; (void)ws_size;
    const int* sIdx = (const int*)d_in[0];
    const int* depT = (const int*)d_in[1];
    const float* DT = (const float*)d_in[2];
    const float* h0 = (const float*)d_in[3];
    const float* emb = (const float*)d_in[4];
    const float* q = (const float*)d_in[5];
    const float* W = (const float*)d_in[6];
    const float* U = (const float*)d_in[7];
    const float* Dm = (const float*)d_in[8];
    const float* b = (const float*)d_in[9];
    const float* Wih = (const float*)d_in[10];
    const float* Whh = (const float*)d_in[11];
    const float* bih = (const float*)d_in[12];
    const float* bhh = (const float*)d_in[13];
    const float* gateW = (const float*)d_in[14];
    const float* gateU = (const float*)d_in[15];
    const float* gateb = (const float*)d_in[16];
    const float* mlpW = (const float*)d_in[17];
    const float* mlpb = (const float*)d_in[18];
    const float* outW = (const float*)d_in[19];
    const float* outb = (const float*)d_in[20];

    char* ws = (char*)d_ws;
    unsigned short* Wb = (unsigned short*)ws;   ws += 768 * 320 * 2;
    _Float16* Uh = (_Float16*)ws;               ws += 768 * 256 * 2;
    _Float16* Wihh = (_Float16*)ws;             ws += 768 * 256 * 2;
    _Float16* Whhh = (_Float16*)ws;             ws += 768 * 256 * 2;
    float* Dq = (float*)ws;                     ws += 10 * 768 * 4;
    float* tv = (float*)ws;                     ws += 1024;
    ws = (char*)d_ws + ((((size_t)(ws - (char*)d_ws)) + 4095) & ~(size_t)4095);
    unsigned short* pre = (unsigned short*)ws;  ws += (size_t)65536 * 768 * 2;
    float* gi = (float*)ws;                     ws += (size_t)1024 * 768 * 4;

    k_prep<<<dim3(799), dim3(256), 0, stream>>>(W, U, Wih, Whh, q, Dm, DT, mlpW, mlpb,
                                                Wb, Uh, Wihh, Whhh, Dq, tv);
    k_phaseB<<<dim3(2048), dim3(256), 0, stream>>>(sIdx, depT, emb, Wb, Dq, b, pre);
    k_phaseC<<<dim3(64), dim3(768), 0, stream>>>(pre, Uh, Wihh, bih, gi);
    k_gru<<<dim3(1), dim3(768), 0, stream>>>(Whhh, bhh, gi, h0, tv,
                                             gateW, gateU, gateb, outW, outb, (float*)d_out);
}

// Round 4
// 1876.946 us; speedup vs baseline: 2.5911x; 2.5911x over previous
//
#include <hip/hip_runtime.h>

typedef short short8 __attribute__((ext_vector_type(8)));
typedef float f4 __attribute__((ext_vector_type(4)));
typedef _Float16 half8 __attribute__((ext_vector_type(8)));
typedef _Float16 h2 __attribute__((ext_vector_type(2)));

#define HD 256
#define ED 300
#define EP 320
#define TH 768
#define NS 1024
#define LW 64

__device__ __forceinline__ unsigned short f2bf(float f) {
    unsigned int u = __float_as_uint(f);
    u = (u + 0x7FFFu + ((u >> 16) & 1u)) >> 16;
    return (unsigned short)u;
}
__device__ __forceinline__ float bf2f(unsigned short s) {
    return __uint_as_float(((unsigned int)s) << 16);
}
__device__ __forceinline__ float sigm(float x) {
    return __builtin_amdgcn_rcpf(1.f + __expf(-x));
}
__device__ __forceinline__ float tanh_(float x) {
    x = fminf(fmaxf(x, -15.f), 15.f);
    return 1.f - 2.f * __builtin_amdgcn_rcpf(1.f + __expf(2.f * x));
}
__device__ __forceinline__ unsigned int pack_h2(float a, float b) {
    h2 p; p.x = (_Float16)a; p.y = (_Float16)b;
    return __builtin_bit_cast(unsigned int, p);
}

__device__ __forceinline__ void load8bf(const unsigned short* p, float* o) {
    uint4 a = *(const uint4*)p;
    o[0] = bf2f((unsigned short)(a.x & 0xffff)); o[1] = bf2f((unsigned short)(a.x >> 16));
    o[2] = bf2f((unsigned short)(a.y & 0xffff)); o[3] = bf2f((unsigned short)(a.y >> 16));
    o[4] = bf2f((unsigned short)(a.z & 0xffff)); o[5] = bf2f((unsigned short)(a.z >> 16));
    o[6] = bf2f((unsigned short)(a.w & 0xffff)); o[7] = bf2f((unsigned short)(a.w >> 16));
}
__device__ __forceinline__ void load4bf(const unsigned short* p, float* o) {
    uint2 a = *(const uint2*)p;
    o[0] = bf2f((unsigned short)(a.x & 0xffff)); o[1] = bf2f((unsigned short)(a.x >> 16));
    o[2] = bf2f((unsigned short)(a.y & 0xffff)); o[3] = bf2f((unsigned short)(a.y >> 16));
}

// ---------------- prep: weight conversions, Dq table, topic vector ----------------
__global__ void k_prep(const float* __restrict__ W, const float* __restrict__ U,
                       const float* __restrict__ Wih, const float* __restrict__ Whh,
                       const float* __restrict__ q, const float* __restrict__ Dm,
                       const float* __restrict__ DT, const float* __restrict__ mlpW,
                       const float* __restrict__ mlpb,
                       unsigned short* __restrict__ Wb, _Float16* __restrict__ Uh,
                       _Float16* __restrict__ Wihh, _Float16* __restrict__ Whhh,
                       float* __restrict__ Dq, float* __restrict__ tv) {
    int bid = blockIdx.x, tid = threadIdx.x;
    if (bid < 768) {
        int r = bid;
        for (int j = tid; j < EP; j += 256)
            Wb[r * EP + j] = (j < ED) ? f2bf(W[r * ED + j]) : (unsigned short)0;
        for (int j = tid; j < HD; j += 256) {
            Uh[r * HD + j] = (_Float16)U[r * HD + j];
            Wihh[r * HD + j] = (_Float16)Wih[r * HD + j];
            Whhh[r * HD + j] = (_Float16)Whh[r * HD + j];
        }
    } else if (bid < 798) {
        int idx = bid - 768;
        int d = idx / 3, part = idx - d * 3;
        int n = part * 256 + tid;
        float s = 0.f;
        for (int h = 0; h < HD; ++h) s += Dm[n * HD + h] * q[d * HD + h];
        Dq[d * TH + n] = s;
    } else {
        if (tid < HD) {
            float s = 0.f;
            for (int k = 0; k < 100; ++k) s += mlpW[tid * 100 + k] * DT[k];
            tv[tid] = tanh_(s + mlpb[tid]);
        }
    }
}

// ---------------- phase B: pre[m][n] = (x @ W^T)[m][n] + Dq_table[dep(m)][n] + b[n] ----------------
__launch_bounds__(256, 2)
__global__ void k_phaseB(const int* __restrict__ sIdx, const int* __restrict__ depT,
                         const float* __restrict__ emb, const unsigned short* __restrict__ Wb,
                         const float* __restrict__ Dq, const float* __restrict__ bias,
                         unsigned short* __restrict__ pre) {
    __shared__ float dq_s[10 * 772];
    __shared__ float b_s[TH];
    __shared__ int dep_s[32];
    __shared__ int idx_s[32];
    int tid = threadIdx.x;
    int c0 = blockIdx.x * 32;
    for (int i = tid; i < 10 * 768; i += 256) {
        int d = i / 768, n = i - d * 768;
        dq_s[d * 772 + n] = Dq[i];
    }
    for (int i = tid; i < TH; i += 256) b_s[i] = bias[i];
    if (tid < 32) {
        int m = c0 + tid;
        idx_s[tid] = sIdx[m];
        int l = m & 63, s = m >> 6;
        dep_s[tid] = (l == 63) ? 9 : depT[s * 63 + l];
    }
    __syncthreads();

    int lane = tid & 63;
    int w = tid >> 6;
    int quad = lane >> 4, l16 = lane & 15;

    const float* xr0 = emb + (long)idx_s[l16] * ED;
    const float* xr1 = emb + (long)idx_s[16 + l16] * ED;

    f4 acc[2][12];
#pragma unroll
    for (int cs = 0; cs < 2; ++cs)
#pragma unroll
        for (int ms = 0; ms < 12; ++ms) acc[cs][ms] = (f4){0.f, 0.f, 0.f, 0.f};

    const unsigned short* wbase = Wb + (w * 192 + l16) * EP;

#pragma unroll
    for (int kt = 0; kt < 10; ++kt) {
        int k0 = kt * 32 + quad * 8;
        short8 bf[2];
#pragma unroll
        for (int cs = 0; cs < 2; ++cs) {
            const float* xr = cs ? xr1 : xr0;
            float xv[8];
            if (k0 + 8 <= ED) {
                float4 f0 = *(const float4*)(xr + k0);
                float4 f1 = *(const float4*)(xr + k0 + 4);
                xv[0] = f0.x; xv[1] = f0.y; xv[2] = f0.z; xv[3] = f0.w;
                xv[4] = f1.x; xv[5] = f1.y; xv[6] = f1.z; xv[7] = f1.w;
            } else {
#pragma unroll
                for (int j = 0; j < 8; ++j) xv[j] = (k0 + j < ED) ? xr[k0 + j] : 0.f;
            }
            short8 t;
#pragma unroll
            for (int j = 0; j < 8; ++j) t[j] = (short)f2bf(xv[j]);
            bf[cs] = t;
        }
#pragma unroll
        for (int ms = 0; ms < 12; ++ms) {
            short8 af = *(const short8*)(wbase + ms * 16 * EP + k0);
            acc[0][ms] = __builtin_amdgcn_mfma_f32_16x16x32_bf16(af, bf[0], acc[0][ms], 0, 0, 0);
            acc[1][ms] = __builtin_amdgcn_mfma_f32_16x16x32_bf16(af, bf[1], acc[1][ms], 0, 0, 0);
        }
    }

#pragma unroll
    for (int cs = 0; cs < 2; ++cs) {
        int xr = c0 + cs * 16 + l16;
        int dep = dep_s[cs * 16 + l16];
        unsigned short* prow = pre + (long)xr * TH;
#pragma unroll
        for (int ms = 0; ms < 12; ++ms) {
            int ncol = w * 192 + ms * 16 + quad * 4;
            f4 dq4 = *(const f4*)&dq_s[dep * 772 + ncol];
            f4 b4 = *(const f4*)&b_s[ncol];
            unsigned int lo = (unsigned int)f2bf(acc[cs][ms][0] + dq4[0] + b4[0]) |
                              ((unsigned int)f2bf(acc[cs][ms][1] + dq4[1] + b4[1]) << 16);
            unsigned int hi = (unsigned int)f2bf(acc[cs][ms][2] + dq4[2] + b4[2]) |
                              ((unsigned int)f2bf(acc[cs][ms][3] + dq4[3] + b4[3]) << 16);
            uint2 v; v.x = lo; v.y = hi;
            *(uint2*)(prow + ncol) = v;
        }
    }
}

// ---------------- phase C v4: U register-resident via waves_per_eu(3,3), 16 sentences/WG ----------------
// waves_per_eu(3,3): cap scheduler occupancy target at 3 waves/EU (exactly this block)
// so the 128-VGPR U fragment set stays hoisted in registers instead of being
// re-loaded from L2 every step (the round-2/3 pathology: VGPR_Count pinned at 84).
__attribute__((amdgpu_waves_per_eu(3, 3)))
__global__ void __launch_bounds__(768) k_phaseC(
                         const unsigned short* __restrict__ pre,
                         const _Float16* __restrict__ Uh,
                         const _Float16* __restrict__ Wihh,
                         const float* __restrict__ bih,
                         float* __restrict__ gi) {
    __shared__ __align__(16) uint4 hfr[512];        // [kt][lane] B-fragments of h
    __shared__ __align__(16) float tot[16 * 772];   // [sentence][row] (padded)
    int tid = threadIdx.x;
    int lane = tid & 63, w = tid >> 6, quad = lane >> 4, l16 = lane & 15;
    int s0 = blockIdx.x * 16;

    uint4 frag[32];
    {
        const _Float16* base = Uh + (w * 64 + l16) * HD;
#pragma unroll
        for (int t = 0; t < 4; ++t)
#pragma unroll
            for (int kt = 0; kt < 8; ++kt)
                frag[t * 8 + kt] = *(const uint4*)(base + t * 16 * HD + kt * 32 + quad * 8);
    }

    int us = tid >> 5;           // sentence (tid<512)
    int jg = tid & 31;
    int j0 = jg * 8;
    int hcell = (j0 >> 5) * 64 + 16 * ((j0 >> 3) & 3) + us;
    uint4 hcp;                    // this thread's 8 h values, packed f16x2

    if (tid < 512) {
        const unsigned short* prow = pre + ((long)(s0 + us) * LW + 63) * TH;
        float iv[8], uv[8], hcv[8];
        load8bf(prow + 256 + j0, iv);
        load8bf(prow + 512 + j0, uv);
#pragma unroll
        for (int r = 0; r < 8; ++r) hcv[r] = tanh_(sigm(iv[r]) * tanh_(uv[r]));
        hcp.x = pack_h2(hcv[0], hcv[1]); hcp.y = pack_h2(hcv[2], hcv[3]);
        hcp.z = pack_h2(hcv[4], hcv[5]); hcp.w = pack_h2(hcv[6], hcv[7]);
        hfr[hcell] = hcp;
    }
    __syncthreads();

    int mb = w * 64 + quad * 4;

    for (int step = 0; step < 63; ++step) {
        int l = 62 - step;
        f4 a0 = (f4){0,0,0,0}, a1 = (f4){0,0,0,0}, a2 = (f4){0,0,0,0}, a3 = (f4){0,0,0,0};
#pragma unroll
        for (int kt = 0; kt < 8; ++kt) {
            half8 b = __builtin_bit_cast(half8, hfr[kt * 64 + lane]);
            a0 = __builtin_amdgcn_mfma_f32_16x16x32_f16(__builtin_bit_cast(half8, frag[kt]), b, a0, 0, 0, 0);
            a1 = __builtin_amdgcn_mfma_f32_16x16x32_f16(__builtin_bit_cast(half8, frag[8 + kt]), b, a1, 0, 0, 0);
            a2 = __builtin_amdgcn_mfma_f32_16x16x32_f16(__builtin_bit_cast(half8, frag[16 + kt]), b, a2, 0, 0, 0);
            a3 = __builtin_amdgcn_mfma_f32_16x16x32_f16(__builtin_bit_cast(half8, frag[24 + kt]), b, a3, 0, 0, 0);
        }
        float* tr = tot + l16 * 772;
        *(f4*)&tr[mb] = a0;
        *(f4*)&tr[mb + 16] = a1;
        *(f4*)&tr[mb + 32] = a2;
        *(f4*)&tr[mb + 48] = a3;
        __syncthreads();
        if (tid < 512) {
            const unsigned short* prow = pre + ((long)(s0 + us) * LW + l) * TH;
            const float* ts = tot + us * 772;
            float hcv[8];
            h2 px = __builtin_bit_cast(h2, hcp.x); h2 py = __builtin_bit_cast(h2, hcp.y);
            h2 pz = __builtin_bit_cast(h2, hcp.z); h2 pw = __builtin_bit_cast(h2, hcp.w);
            hcv[0] = (float)px.x; hcv[1] = (float)px.y; hcv[2] = (float)py.x; hcv[3] = (float)py.y;
            hcv[4] = (float)pz.x; hcv[5] = (float)pz.y; hcv[6] = (float)pw.x; hcv[7] = (float)pw.y;
#pragma unroll
            for (int hf = 0; hf < 2; ++hf) {
                int jb = j0 + hf * 4;
                float pf[4], pi_[4], pu[4];
                load4bf(prow + jb, pf);
                load4bf(prow + 256 + jb, pi_);
                load4bf(prow + 512 + jb, pu);
                f4 tf = *(const f4*)&ts[jb];
                f4 ti = *(const f4*)&ts[256 + jb];
                f4 tu = *(const f4*)&ts[512 + jb];
#pragma unroll
                for (int r = 0; r < 4; ++r) {
                    float ff = tf[r] + pf[r];
                    float ii = ti[r] + pi_[r];
                    float uu = tu[r] + pu[r];
                    hcv[hf * 4 + r] = tanh_(sigm(ii) * tanh_(uu) + sigm(ff) * hcv[hf * 4 + r]);
                }
            }
            hcp.x = pack_h2(hcv[0], hcv[1]); hcp.y = pack_h2(hcv[2], hcv[3]);
            hcp.z = pack_h2(hcv[4], hcv[5]); hcp.w = pack_h2(hcv[6], hcv[7]);
            hfr[hcell] = hcp;
        }
        __syncthreads();
    }

    // epilogue: gi[s] = Wih @ sv_s + bih, reuse frag regs for Wih
    {
        const _Float16* base = Wihh + (w * 64 + l16) * HD;
#pragma unroll
        for (int t = 0; t < 4; ++t)
#pragma unroll
            for (int kt = 0; kt < 8; ++kt)
                frag[t * 8 + kt] = *(const uint4*)(base + t * 16 * HD + kt * 32 + quad * 8);
    }
    f4 a0 = (f4){0,0,0,0}, a1 = (f4){0,0,0,0}, a2 = (f4){0,0,0,0}, a3 = (f4){0,0,0,0};
#pragma unroll
    for (int kt = 0; kt < 8; ++kt) {
        half8 b = __builtin_bit_cast(half8, hfr[kt * 64 + lane]);
        a0 = __builtin_amdgcn_mfma_f32_16x16x32_f16(__builtin_bit_cast(half8, frag[kt]), b, a0, 0, 0, 0);
        a1 = __builtin_amdgcn_mfma_f32_16x16x32_f16(__builtin_bit_cast(half8, frag[8 + kt]), b, a1, 0, 0, 0);
        a2 = __builtin_amdgcn_mfma_f32_16x16x32_f16(__builtin_bit_cast(half8, frag[16 + kt]), b, a2, 0, 0, 0);
        a3 = __builtin_amdgcn_mfma_f32_16x16x32_f16(__builtin_bit_cast(half8, frag[24 + kt]), b, a3, 0, 0, 0);
    }
    float* go = gi + (long)(s0 + l16) * TH;
    f4 b0 = *(const f4*)(bih + mb);
    f4 b1 = *(const f4*)(bih + mb + 16);
    f4 b2 = *(const f4*)(bih + mb + 32);
    f4 b3 = *(const f4*)(bih + mb + 48);
    *(f4*)(go + mb) = a0 + b0;
    *(f4*)(go + mb + 16) = a1 + b1;
    *(f4*)(go + mb + 32) = a2 + b2;
    *(f4*)(go + mb + 48) = a3 + b3;
}

// ---------------- GRU v4: MFMA matvec, Whh register-resident via waves_per_eu(3,3) ----------------
__attribute__((amdgpu_waves_per_eu(3, 3)))
__global__ void __launch_bounds__(768) k_gru(
                      const _Float16* __restrict__ Whhh, const float* __restrict__ bhh,
                      const float* __restrict__ gi, const float* __restrict__ h0,
                      const float* __restrict__ tv,
                      const float* __restrict__ gateW, const float* __restrict__ gateU,
                      const float* __restrict__ gateb,
                      const float* __restrict__ outW, const float* __restrict__ outb,
                      float* __restrict__ out) {
    __shared__ __align__(16) _Float16 hb[HD];
    __shared__ __align__(16) float ghs[TH];
    __shared__ float hts[HD];
    __shared__ float sgs[512];
    __shared__ float vvs[HD];
    __shared__ float lg[8];

    int tid = threadIdx.x;
    int lane = tid & 63, w = tid >> 6, quad = lane >> 4, l16 = lane & 15;

    uint4 frag[32];
    {
        const _Float16* base = Whhh + (long)(w * 64 + l16) * HD;
#pragma unroll
        for (int t = 0; t < 4; ++t)
#pragma unroll
            for (int kt = 0; kt < 8; ++kt)
                frag[t * 8 + kt] = *(const uint4*)(base + t * 16 * HD + kt * 32 + quad * 8);
    }

    float br = 0.f, bz = 0.f, bn = 0.f, hj = 0.f;
    if (tid < HD) {
        hj = h0[tid];
        hb[tid] = (_Float16)hj;
        br = bhh[tid]; bz = bhh[256 + tid]; bn = bhh[512 + tid];
    }
    __syncthreads();

    int gb = w * 64 + quad * 4;

    for (int t = 0; t < NS; ++t) {
        float gr = 0.f, gz = 0.f, gn = 0.f;
        if (tid < HD) {
            const float* g = gi + (long)t * TH + tid;
            gr = g[0]; gz = g[256]; gn = g[512];
        }
        f4 a0 = (f4){0,0,0,0}, a1 = (f4){0,0,0,0}, a2 = (f4){0,0,0,0}, a3 = (f4){0,0,0,0};
#pragma unroll
        for (int kt = 0; kt < 8; ++kt) {
            half8 b = __builtin_bit_cast(half8, *(const uint4*)&hb[kt * 32 + quad * 8]);
            a0 = __builtin_amdgcn_mfma_f32_16x16x32_f16(__builtin_bit_cast(half8, frag[kt]), b, a0, 0, 0, 0);
            a1 = __builtin_amdgcn_mfma_f32_16x16x32_f16(__builtin_bit_cast(half8, frag[8 + kt]), b, a1, 0, 0, 0);
            a2 = __builtin_amdgcn_mfma_f32_16x16x32_f16(__builtin_bit_cast(half8, frag[16 + kt]), b, a2, 0, 0, 0);
            a3 = __builtin_amdgcn_mfma_f32_16x16x32_f16(__builtin_bit_cast(half8, frag[24 + kt]), b, a3, 0, 0, 0);
        }
        if (l16 == 0) {
            *(f4*)&ghs[gb] = a0;
            *(f4*)&ghs[gb + 16] = a1;
            *(f4*)&ghs[gb + 32] = a2;
            *(f4*)&ghs[gb + 48] = a3;
        }
        __syncthreads();
        if (tid < HD) {
            float r = sigm(gr + ghs[tid] + br);
            float z = sigm(gz + ghs[256 + tid] + bz);
            float n = tanh_(gn + r * (ghs[512 + tid] + bn));
            hj = (1.f - z) * n + z * hj;
            hb[tid] = (_Float16)hj;
        }
        __syncthreads();
    }

    // head
    if (tid < HD) hts[tid] = hj;
    __syncthreads();
    if (tid < 512) {
        float s = gateb[tid];
        for (int k = 0; k < HD; ++k)
            s += gateW[tid * HD + k] * hts[k] + gateU[tid * HD + k] * tv[k];
        sgs[tid] = sigm(s);
    }
    __syncthreads();
    if (tid < HD) vvs[tid] = tanh_(sgs[tid] * hts[tid] + sgs[256 + tid] * tv[tid]);
    __syncthreads();
    if (tid < 5) {
        float s = outb[tid];
        for (int k = 0; k < HD; ++k) s += outW[tid * HD + k] * vvs[k];
        lg[tid] = s;
    }
    __syncthreads();
    if (tid == 0) {
        float m = lg[0];
        for (int i = 1; i < 5; ++i) m = fmaxf(m, lg[i]);
        float e[5], sum = 0.f;
        for (int i = 0; i < 5; ++i) { e[i] = __expf(lg[i] - m); sum += e[i]; }
        for (int i = 0; i < 5; ++i) out[i] = e[i] / sum;
    }
}

extern "C" void kernel_launch(void* const* d_in, const int* in_sizes, int n_in,
                              void* d_out, int out_size, void* d_ws, size_t ws_size,
                              hipStream_t stream) {
    (void)in_sizes; (void)n_in; (void)out_size; (void)ws_size;
    const int* sIdx = (const int*)d_in[0];
    const int* depT = (const int*)d_in[1];
    const float* DT = (const float*)d_in[2];
    const float* h0 = (const float*)d_in[3];
    const float* emb = (const float*)d_in[4];
    const float* q = (const float*)d_in[5];
    const float* W = (const float*)d_in[6];
    const float* U = (const float*)d_in[7];
    const float* Dm = (const float*)d_in[8];
    const float* b = (const float*)d_in[9];
    const float* Wih = (const float*)d_in[10];
    const float* Whh = (const float*)d_in[11];
    const float* bih = (const float*)d_in[12];
    const float* bhh = (const float*)d_in[13];
    const float* gateW = (const float*)d_in[14];
    const float* gateU = (const float*)d_in[15];
    const float* gateb = (const float*)d_in[16];
    const float* mlpW = (const float*)d_in[17];
    const float* mlpb = (const float*)d_in[18];
    const float* outW = (const float*)d_in[19];
    const float* outb = (const float*)d_in[20];

    char* ws = (char*)d_ws;
    unsigned short* Wb = (unsigned short*)ws;   ws += 768 * 320 * 2;
    _Float16* Uh = (_Float16*)ws;               ws += 768 * 256 * 2;
    _Float16* Wihh = (_Float16*)ws;             ws += 768 * 256 * 2;
    _Float16* Whhh = (_Float16*)ws;             ws += 768 * 256 * 2;
    float* Dq = (float*)ws;                     ws += 10 * 768 * 4;
    float* tv = (float*)ws;                     ws += 1024;
    ws = (char*)d_ws + ((((size_t)(ws - (char*)d_ws)) + 4095) & ~(size_t)4095);
    unsigned short* pre = (unsigned short*)ws;  ws += (size_t)65536 * 768 * 2;
    float* gi = (float*)ws;                     ws += (size_t)1024 * 768 * 4;

    k_prep<<<dim3(799), dim3(256), 0, stream>>>(W, U, Wih, Whh, q, Dm, DT, mlpW, mlpb,
                                                Wb, Uh, Wihh, Whhh, Dq, tv);
    k_phaseB<<<dim3(2048), dim3(256), 0, stream>>>(sIdx, depT, emb, Wb, Dq, b, pre);
    k_phaseC<<<dim3(64), dim3(768), 0, stream>>>(pre, Uh, Wihh, bih, gi);
    k_gru<<<dim3(1), dim3(768), 0, stream>>>(Whhh, bhh, gi, h0, tv,
                                             gateW, gateU, gateb, outW, outb, (float*)d_out);
}

// Round 5
// 1702.250 us; speedup vs baseline: 2.8570x; 1.1026x over previous
//
#include <hip/hip_runtime.h>

typedef short short8 __attribute__((ext_vector_type(8)));
typedef float f4 __attribute__((ext_vector_type(4)));
typedef int i4 __attribute__((ext_vector_type(4)));
typedef _Float16 half8 __attribute__((ext_vector_type(8)));
typedef _Float16 h2 __attribute__((ext_vector_type(2)));

#define HD 256
#define ED 300
#define EP 320
#define TH 768
#define NS 1024
#define LW 64
#define SH 4.5f

__device__ __forceinline__ unsigned short f2bf(float f) {
    unsigned int u = __float_as_uint(f);
    u = (u + 0x7FFFu + ((u >> 16) & 1u)) >> 16;
    return (unsigned short)u;
}
__device__ __forceinline__ float bf2f(unsigned short s) {
    return __uint_as_float(((unsigned int)s) << 16);
}
__device__ __forceinline__ float sigm(float x) {
    return __builtin_amdgcn_rcpf(1.f + __expf(-x));
}
__device__ __forceinline__ float tanh_(float x) {
    x = fminf(fmaxf(x, -15.f), 15.f);
    return 1.f - 2.f * __builtin_amdgcn_rcpf(1.f + __expf(2.f * x));
}
__device__ __forceinline__ unsigned int pack_h2(float a, float b) {
    h2 p; p.x = (_Float16)a; p.y = (_Float16)b;
    return __builtin_bit_cast(unsigned int, p);
}

__device__ __forceinline__ void load8bf(const unsigned short* p, float* o) {
    uint4 a = *(const uint4*)p;
    o[0] = bf2f((unsigned short)(a.x & 0xffff)); o[1] = bf2f((unsigned short)(a.x >> 16));
    o[2] = bf2f((unsigned short)(a.y & 0xffff)); o[3] = bf2f((unsigned short)(a.y >> 16));
    o[4] = bf2f((unsigned short)(a.z & 0xffff)); o[5] = bf2f((unsigned short)(a.z >> 16));
    o[6] = bf2f((unsigned short)(a.w & 0xffff)); o[7] = bf2f((unsigned short)(a.w >> 16));
}
__device__ __forceinline__ void load4bf(const unsigned short* p, float* o) {
    uint2 a = *(const uint2*)p;
    o[0] = bf2f((unsigned short)(a.x & 0xffff)); o[1] = bf2f((unsigned short)(a.x >> 16));
    o[2] = bf2f((unsigned short)(a.y & 0xffff)); o[3] = bf2f((unsigned short)(a.y >> 16));
}

// ---------------- prep: weight conversions, i8 quantization, Dq table, topic vector ----------------
__global__ void k_prep(const float* __restrict__ W, const float* __restrict__ U,
                       const float* __restrict__ Wih, const float* __restrict__ Whh,
                       const float* __restrict__ q, const float* __restrict__ Dm,
                       const float* __restrict__ DT, const float* __restrict__ mlpW,
                       const float* __restrict__ mlpb,
                       unsigned short* __restrict__ Wb, _Float16* __restrict__ Uh,
                       _Float16* __restrict__ Wihh, _Float16* __restrict__ Whhh,
                       signed char* __restrict__ Wq, float* __restrict__ rowscale,
                       float* __restrict__ Dq, float* __restrict__ tv) {
    __shared__ float smax[4];
    int bid = blockIdx.x, tid = threadIdx.x;
    if (bid < 768) {
        int r = bid;
        for (int j = tid; j < EP; j += 256)
            Wb[r * EP + j] = (j < ED) ? f2bf(W[r * ED + j]) : (unsigned short)0;
        float whv = Whh[r * HD + tid];
        for (int j = tid; j < HD; j += 256) {
            Uh[r * HD + j] = (_Float16)U[r * HD + j];
            Wihh[r * HD + j] = (_Float16)Wih[r * HD + j];
            Whhh[r * HD + j] = (_Float16)Whh[r * HD + j];
        }
        if (r < 512) {
            // per-row i8 quantization of Whh rows 0..511 (r/z gates)
            float v = fabsf(whv);
            for (int o = 32; o; o >>= 1) v = fmaxf(v, __shfl_xor(v, o));
            if ((tid & 63) == 0) smax[tid >> 6] = v;
            __syncthreads();
            float am = fmaxf(fmaxf(smax[0], smax[1]), fmaxf(smax[2], smax[3]));
            float inv = (am > 0.f) ? 127.f / am : 0.f;
            int qi = (int)rintf(whv * inv);
            qi = max(-127, min(127, qi));
            Wq[r * HD + tid] = (signed char)qi;
            if (tid == 0) rowscale[r] = (am / 127.f) * (SH / 127.f);
        }
    } else if (bid < 798) {
        int idx = bid - 768;
        int d = idx / 3, part = idx - d * 3;
        int n = part * 256 + tid;
        float s = 0.f;
        for (int h = 0; h < HD; ++h) s += Dm[n * HD + h] * q[d * HD + h];
        Dq[d * TH + n] = s;
    } else {
        if (tid < HD) {
            float s = 0.f;
            for (int k = 0; k < 100; ++k) s += mlpW[tid * 100 + k] * DT[k];
            tv[tid] = tanh_(s + mlpb[tid]);
        }
    }
}

// ---------------- phase B: pre[m][n] = (x @ W^T)[m][n] + Dq_table[dep(m)][n] + b[n] ----------------
__launch_bounds__(256, 2)
__global__ void k_phaseB(const int* __restrict__ sIdx, const int* __restrict__ depT,
                         const float* __restrict__ emb, const unsigned short* __restrict__ Wb,
                         const float* __restrict__ Dq, const float* __restrict__ bias,
                         unsigned short* __restrict__ pre) {
    __shared__ float dq_s[10 * 772];
    __shared__ float b_s[TH];
    __shared__ int dep_s[32];
    __shared__ int idx_s[32];
    int tid = threadIdx.x;
    int c0 = blockIdx.x * 32;
    for (int i = tid; i < 10 * 768; i += 256) {
        int d = i / 768, n = i - d * 768;
        dq_s[d * 772 + n] = Dq[i];
    }
    for (int i = tid; i < TH; i += 256) b_s[i] = bias[i];
    if (tid < 32) {
        int m = c0 + tid;
        idx_s[tid] = sIdx[m];
        int l = m & 63, s = m >> 6;
        dep_s[tid] = (l == 63) ? 9 : depT[s * 63 + l];
    }
    __syncthreads();

    int lane = tid & 63;
    int w = tid >> 6;
    int quad = lane >> 4, l16 = lane & 15;

    const float* xr0 = emb + (long)idx_s[l16] * ED;
    const float* xr1 = emb + (long)idx_s[16 + l16] * ED;

    f4 acc[2][12];
#pragma unroll
    for (int cs = 0; cs < 2; ++cs)
#pragma unroll
        for (int ms = 0; ms < 12; ++ms) acc[cs][ms] = (f4){0.f, 0.f, 0.f, 0.f};

    const unsigned short* wbase = Wb + (w * 192 + l16) * EP;

#pragma unroll
    for (int kt = 0; kt < 10; ++kt) {
        int k0 = kt * 32 + quad * 8;
        short8 bf[2];
#pragma unroll
        for (int cs = 0; cs < 2; ++cs) {
            const float* xr = cs ? xr1 : xr0;
            float xv[8];
            if (k0 + 8 <= ED) {
                float4 f0 = *(const float4*)(xr + k0);
                float4 f1 = *(const float4*)(xr + k0 + 4);
                xv[0] = f0.x; xv[1] = f0.y; xv[2] = f0.z; xv[3] = f0.w;
                xv[4] = f1.x; xv[5] = f1.y; xv[6] = f1.z; xv[7] = f1.w;
            } else {
#pragma unroll
                for (int j = 0; j < 8; ++j) xv[j] = (k0 + j < ED) ? xr[k0 + j] : 0.f;
            }
            short8 t;
#pragma unroll
            for (int j = 0; j < 8; ++j) t[j] = (short)f2bf(xv[j]);
            bf[cs] = t;
        }
#pragma unroll
        for (int ms = 0; ms < 12; ++ms) {
            short8 af = *(const short8*)(wbase + ms * 16 * EP + k0);
            acc[0][ms] = __builtin_amdgcn_mfma_f32_16x16x32_bf16(af, bf[0], acc[0][ms], 0, 0, 0);
            acc[1][ms] = __builtin_amdgcn_mfma_f32_16x16x32_bf16(af, bf[1], acc[1][ms], 0, 0, 0);
        }
    }

#pragma unroll
    for (int cs = 0; cs < 2; ++cs) {
        int xr = c0 + cs * 16 + l16;
        int dep = dep_s[cs * 16 + l16];
        unsigned short* prow = pre + (long)xr * TH;
#pragma unroll
        for (int ms = 0; ms < 12; ++ms) {
            int ncol = w * 192 + ms * 16 + quad * 4;
            f4 dq4 = *(const f4*)&dq_s[dep * 772 + ncol];
            f4 b4 = *(const f4*)&b_s[ncol];
            unsigned int lo = (unsigned int)f2bf(acc[cs][ms][0] + dq4[0] + b4[0]) |
                              ((unsigned int)f2bf(acc[cs][ms][1] + dq4[1] + b4[1]) << 16);
            unsigned int hi = (unsigned int)f2bf(acc[cs][ms][2] + dq4[2] + b4[2]) |
                              ((unsigned int)f2bf(acc[cs][ms][3] + dq4[3] + b4[3]) << 16);
            uint2 v; v.x = lo; v.y = hi;
            *(uint2*)(prow + ncol) = v;
        }
    }
}

// ---------------- phase C: U register/AGPR-resident MFMA, 16 sentences/WG ----------------
__global__ void __launch_bounds__(768) k_phaseC(
                         const unsigned short* __restrict__ pre,
                         const _Float16* __restrict__ Uh,
                         const _Float16* __restrict__ Wihh,
                         const float* __restrict__ bih,
                         float* __restrict__ gi) {
    __shared__ __align__(16) uint4 hfr[512];        // [kt][lane] B-fragments of h
    __shared__ __align__(16) float tot[16 * 772];   // [sentence][row] (padded)
    int tid = threadIdx.x;
    int lane = tid & 63, w = tid >> 6, quad = lane >> 4, l16 = lane & 15;
    int s0 = blockIdx.x * 16;

    uint4 frag[32];
    {
        const _Float16* base = Uh + (w * 64 + l16) * HD;
#pragma unroll
        for (int t = 0; t < 4; ++t)
#pragma unroll
            for (int kt = 0; kt < 8; ++kt)
                frag[t * 8 + kt] = *(const uint4*)(base + t * 16 * HD + kt * 32 + quad * 8);
    }

    int us = tid >> 5;           // sentence (tid<512)
    int jg = tid & 31;
    int j0 = jg * 8;
    int hcell = (j0 >> 5) * 64 + 16 * ((j0 >> 3) & 3) + us;
    uint4 hcp;                    // this thread's 8 h values, packed f16x2

    if (tid < 512) {
        const unsigned short* prow = pre + ((long)(s0 + us) * LW + 63) * TH;
        float iv[8], uv[8], hcv[8];
        load8bf(prow + 256 + j0, iv);
        load8bf(prow + 512 + j0, uv);
#pragma unroll
        for (int r = 0; r < 8; ++r) hcv[r] = tanh_(sigm(iv[r]) * tanh_(uv[r]));
        hcp.x = pack_h2(hcv[0], hcv[1]); hcp.y = pack_h2(hcv[2], hcv[3]);
        hcp.z = pack_h2(hcv[4], hcv[5]); hcp.w = pack_h2(hcv[6], hcv[7]);
        hfr[hcell] = hcp;
    }
    __syncthreads();

    int mb = w * 64 + quad * 4;

    for (int step = 0; step < 63; ++step) {
        int l = 62 - step;
        f4 a0 = (f4){0,0,0,0}, a1 = (f4){0,0,0,0}, a2 = (f4){0,0,0,0}, a3 = (f4){0,0,0,0};
#pragma unroll
        for (int kt = 0; kt < 8; ++kt) {
            half8 b = __builtin_bit_cast(half8, hfr[kt * 64 + lane]);
            a0 = __builtin_amdgcn_mfma_f32_16x16x32_f16(__builtin_bit_cast(half8, frag[kt]), b, a0, 0, 0, 0);
            a1 = __builtin_amdgcn_mfma_f32_16x16x32_f16(__builtin_bit_cast(half8, frag[8 + kt]), b, a1, 0, 0, 0);
            a2 = __builtin_amdgcn_mfma_f32_16x16x32_f16(__builtin_bit_cast(half8, frag[16 + kt]), b, a2, 0, 0, 0);
            a3 = __builtin_amdgcn_mfma_f32_16x16x32_f16(__builtin_bit_cast(half8, frag[24 + kt]), b, a3, 0, 0, 0);
        }
        float* tr = tot + l16 * 772;
        *(f4*)&tr[mb] = a0;
        *(f4*)&tr[mb + 16] = a1;
        *(f4*)&tr[mb + 32] = a2;
        *(f4*)&tr[mb + 48] = a3;
        __syncthreads();
        if (tid < 512) {
            const unsigned short* prow = pre + ((long)(s0 + us) * LW + l) * TH;
            const float* ts = tot + us * 772;
            float hcv[8];
            h2 px = __builtin_bit_cast(h2, hcp.x); h2 py = __builtin_bit_cast(h2, hcp.y);
            h2 pz = __builtin_bit_cast(h2, hcp.z); h2 pw = __builtin_bit_cast(h2, hcp.w);
            hcv[0] = (float)px.x; hcv[1] = (float)px.y; hcv[2] = (float)py.x; hcv[3] = (float)py.y;
            hcv[4] = (float)pz.x; hcv[5] = (float)pz.y; hcv[6] = (float)pw.x; hcv[7] = (float)pw.y;
#pragma unroll
            for (int hf = 0; hf < 2; ++hf) {
                int jb = j0 + hf * 4;
                float pf[4], pi_[4], pu[4];
                load4bf(prow + jb, pf);
                load4bf(prow + 256 + jb, pi_);
                load4bf(prow + 512 + jb, pu);
                f4 tf = *(const f4*)&ts[jb];
                f4 ti = *(const f4*)&ts[256 + jb];
                f4 tu = *(const f4*)&ts[512 + jb];
#pragma unroll
                for (int r = 0; r < 4; ++r) {
                    float ff = tf[r] + pf[r];
                    float ii = ti[r] + pi_[r];
                    float uu = tu[r] + pu[r];
                    hcv[hf * 4 + r] = tanh_(sigm(ii) * tanh_(uu) + sigm(ff) * hcv[hf * 4 + r]);
                }
            }
            hcp.x = pack_h2(hcv[0], hcv[1]); hcp.y = pack_h2(hcv[2], hcv[3]);
            hcp.z = pack_h2(hcv[4], hcv[5]); hcp.w = pack_h2(hcv[6], hcv[7]);
            hfr[hcell] = hcp;
        }
        __syncthreads();
    }

    // epilogue: gi[s] = Wih @ sv_s + bih, reuse frag regs for Wih
    {
        const _Float16* base = Wihh + (w * 64 + l16) * HD;
#pragma unroll
        for (int t = 0; t < 4; ++t)
#pragma unroll
            for (int kt = 0; kt < 8; ++kt)
                frag[t * 8 + kt] = *(const uint4*)(base + t * 16 * HD + kt * 32 + quad * 8);
    }
    f4 a0 = (f4){0,0,0,0}, a1 = (f4){0,0,0,0}, a2 = (f4){0,0,0,0}, a3 = (f4){0,0,0,0};
#pragma unroll
    for (int kt = 0; kt < 8; ++kt) {
        half8 b = __builtin_bit_cast(half8, hfr[kt * 64 + lane]);
        a0 = __builtin_amdgcn_mfma_f32_16x16x32_f16(__builtin_bit_cast(half8, frag[kt]), b, a0, 0, 0, 0);
        a1 = __builtin_amdgcn_mfma_f32_16x16x32_f16(__builtin_bit_cast(half8, frag[8 + kt]), b, a1, 0, 0, 0);
        a2 = __builtin_amdgcn_mfma_f32_16x16x32_f16(__builtin_bit_cast(half8, frag[16 + kt]), b, a2, 0, 0, 0);
        a3 = __builtin_amdgcn_mfma_f32_16x16x32_f16(__builtin_bit_cast(half8, frag[24 + kt]), b, a3, 0, 0, 0);
    }
    float* go = gi + (long)(s0 + l16) * TH;
    f4 b0 = *(const f4*)(bih + mb);
    f4 b1 = *(const f4*)(bih + mb + 16);
    f4 b2 = *(const f4*)(bih + mb + 32);
    f4 b3 = *(const f4*)(bih + mb + 48);
    *(f4*)(go + mb) = a0 + b0;
    *(f4*)(go + mb + 16) = a1 + b1;
    *(f4*)(go + mb + 32) = a2 + b2;
    *(f4*)(go + mb + 48) = a3 + b3;
}

// ---------------- GRU v5: mixed i8(r,z)+f16(n) MFMA matvec, 1024 threads, 1024 steps + head ----------------
// r/z rows 0..511 in i8 (sigmoid slope <= 1/4 protects error); n rows 512..767 in f16.
// Pipe floor per step: 32 i8 MFMA (18.3 cyc) + 32 f16 MFMA (16.9 cyc) per SIMD ~= 1127 cyc
// vs 1622 for all-f16 (round 4). Per-wave frags: 2 i8 tiles (32 regs) + 1 f16 tile (32 regs).
__attribute__((amdgpu_waves_per_eu(1, 4)))
__global__ void __launch_bounds__(1024) k_gru(
                      const signed char* __restrict__ Wq, const float* __restrict__ rowscale,
                      const _Float16* __restrict__ Whhh, const float* __restrict__ bhh,
                      const float* __restrict__ gi, const float* __restrict__ h0,
                      const float* __restrict__ tv,
                      const float* __restrict__ gateW, const float* __restrict__ gateU,
                      const float* __restrict__ gateb,
                      const float* __restrict__ outW, const float* __restrict__ outb,
                      float* __restrict__ out) {
    __shared__ __align__(16) _Float16 hb[HD];        // h as f16
    __shared__ __align__(16) signed char hq[HD];     // h as i8 (scale SH/127)
    __shared__ __align__(16) float ghs[TH];
    __shared__ float hts[HD];
    __shared__ float sgs[512];
    __shared__ float vvs[HD];
    __shared__ float lg[8];

    int tid = threadIdx.x;
    int lane = tid & 63, w = tid >> 6, quad = lane >> 4, l16 = lane & 15;

    // i8 fragments: wave w owns tiles 2w, 2w+1 (rows 32w .. 32w+31)
    i4 fa0[4], fa1[4];
    {
        const signed char* q0 = Wq + (long)(w * 32 + l16) * HD;
        const signed char* q1 = Wq + (long)(w * 32 + 16 + l16) * HD;
#pragma unroll
        for (int kt = 0; kt < 4; ++kt) {
            fa0[kt] = *(const i4*)(q0 + kt * 64 + quad * 16);
            fa1[kt] = *(const i4*)(q1 + kt * 64 + quad * 16);
        }
    }
    // f16 fragment: wave w owns n-rows 512 + 16w .. 512 + 16w + 15
    uint4 fn[8];
    {
        const _Float16* nb = Whhh + (long)(512 + w * 16 + l16) * HD;
#pragma unroll
        for (int kt = 0; kt < 8; ++kt)
            fn[kt] = *(const uint4*)(nb + kt * 32 + quad * 8);
    }
    // dequant row scales for epilogue (rows of D tiles this lane writes when l16==0)
    f4 rs0 = *(const f4*)(rowscale + w * 32 + quad * 4);
    f4 rs1 = *(const f4*)(rowscale + w * 32 + 16 + quad * 4);

    float br = 0.f, bz = 0.f, bn = 0.f, hj = 0.f;
    if (tid < HD) {
        hj = h0[tid];
        hb[tid] = (_Float16)hj;
        float hc = fminf(fmaxf(hj, -SH), SH);
        int qi = (int)rintf(hc * (127.f / SH));
        hq[tid] = (signed char)qi;
        br = bhh[tid]; bz = bhh[256 + tid]; bn = bhh[512 + tid];
    }
    __syncthreads();

    for (int t = 0; t < NS; ++t) {
        float gr = 0.f, gz = 0.f, gn = 0.f;
        if (tid < HD) {
            const float* g = gi + (long)t * TH + tid;
            gr = g[0]; gz = g[256]; gn = g[512];
        }
        // i8 matvec (r,z rows)
        i4 q0 = (i4){0, 0, 0, 0}, q1 = (i4){0, 0, 0, 0};
#pragma unroll
        for (int kt = 0; kt < 4; ++kt) {
            i4 b = *(const i4*)&hq[kt * 64 + quad * 16];
            q0 = __builtin_amdgcn_mfma_i32_16x16x64_i8(fa0[kt], b, q0, 0, 0, 0);
            q1 = __builtin_amdgcn_mfma_i32_16x16x64_i8(fa1[kt], b, q1, 0, 0, 0);
        }
        // f16 matvec (n rows)
        f4 an = (f4){0, 0, 0, 0};
#pragma unroll
        for (int kt = 0; kt < 8; ++kt) {
            half8 b = __builtin_bit_cast(half8, *(const uint4*)&hb[kt * 32 + quad * 8]);
            an = __builtin_amdgcn_mfma_f32_16x16x32_f16(__builtin_bit_cast(half8, fn[kt]), b, an, 0, 0, 0);
        }
        if (l16 == 0) {
            f4 g0, g1;
#pragma unroll
            for (int r = 0; r < 4; ++r) {
                g0[r] = (float)q0[r] * rs0[r];
                g1[r] = (float)q1[r] * rs1[r];
            }
            *(f4*)&ghs[w * 32 + quad * 4] = g0;
            *(f4*)&ghs[w * 32 + 16 + quad * 4] = g1;
            *(f4*)&ghs[512 + w * 16 + quad * 4] = an;
        }
        __syncthreads();
        if (tid < HD) {
            float r = sigm(gr + ghs[tid] + br);
            float z = sigm(gz + ghs[256 + tid] + bz);
            float n = tanh_(gn + r * (ghs[512 + tid] + bn));
            hj = (1.f - z) * n + z * hj;
            hb[tid] = (_Float16)hj;
            float hc = fminf(fmaxf(hj, -SH), SH);
            int qi = (int)rintf(hc * (127.f / SH));
            hq[tid] = (signed char)qi;
        }
        __syncthreads();
    }

    // head
    if (tid < HD) hts[tid] = hj;
    __syncthreads();
    if (tid < 512) {
        float s = gateb[tid];
        for (int k = 0; k < HD; ++k)
            s += gateW[tid * HD + k] * hts[k] + gateU[tid * HD + k] * tv[k];
        sgs[tid] = sigm(s);
    }
    __syncthreads();
    if (tid < HD) vvs[tid] = tanh_(sgs[tid] * hts[tid] + sgs[256 + tid] * tv[tid]);
    __syncthreads();
    if (tid < 5) {
        float s = outb[tid];
        for (int k = 0; k < HD; ++k) s += outW[tid * HD + k] * vvs[k];
        lg[tid] = s;
    }
    __syncthreads();
    if (tid == 0) {
        float m = lg[0];
        for (int i = 1; i < 5; ++i) m = fmaxf(m, lg[i]);
        float e[5], sum = 0.f;
        for (int i = 0; i < 5; ++i) { e[i] = __expf(lg[i] - m); sum += e[i]; }
        for (int i = 0; i < 5; ++i) out[i] = e[i] / sum;
    }
}

extern "C" void kernel_launch(void* const* d_in, const int* in_sizes, int n_in,
                              void* d_out, int out_size, void* d_ws, size_t ws_size,
                              hipStream_t stream) {
    (void)in_sizes; (void)n_in; (void)out_size; (void)ws_size;
    const int* sIdx = (const int*)d_in[0];
    const int* depT = (const int*)d_in[1];
    const float* DT = (const float*)d_in[2];
    const float* h0 = (const float*)d_in[3];
    const float* emb = (const float*)d_in[4];
    const float* q = (const float*)d_in[5];
    const float* W = (const float*)d_in[6];
    const float* U = (const float*)d_in[7];
    const float* Dm = (const float*)d_in[8];
    const float* b = (const float*)d_in[9];
    const float* Wih = (const float*)d_in[10];
    const float* Whh = (const float*)d_in[11];
    const float* bih = (const float*)d_in[12];
    const float* bhh = (const float*)d_in[13];
    const float* gateW = (const float*)d_in[14];
    const float* gateU = (const float*)d_in[15];
    const float* gateb = (const float*)d_in[16];
    const float* mlpW = (const float*)d_in[17];
    const float* mlpb = (const float*)d_in[18];
    const float* outW = (const float*)d_in[19];
    const float* outb = (const float*)d_in[20];

    char* ws = (char*)d_ws;
    unsigned short* Wb = (unsigned short*)ws;   ws += 768 * 320 * 2;
    _Float16* Uh = (_Float16*)ws;               ws += 768 * 256 * 2;
    _Float16* Wihh = (_Float16*)ws;             ws += 768 * 256 * 2;
    _Float16* Whhh = (_Float16*)ws;             ws += 768 * 256 * 2;
    signed char* Wq = (signed char*)ws;         ws += 512 * 256;
    float* rowscale = (float*)ws;               ws += 512 * 4;
    float* Dq = (float*)ws;                     ws += 10 * 768 * 4;
    float* tv = (float*)ws;                     ws += 1024;
    ws = (char*)d_ws + ((((size_t)(ws - (char*)d_ws)) + 4095) & ~(size_t)4095);
    unsigned short* pre = (unsigned short*)ws;  ws += (size_t)65536 * 768 * 2;
    float* gi = (float*)ws;                     ws += (size_t)1024 * 768 * 4;

    k_prep<<<dim3(799), dim3(256), 0, stream>>>(W, U, Wih, Whh, q, Dm, DT, mlpW, mlpb,
                                                Wb, Uh, Wihh, Whhh, Wq, rowscale, Dq, tv);
    k_phaseB<<<dim3(2048), dim3(256), 0, stream>>>(sIdx, depT, emb, Wb, Dq, b, pre);
    k_phaseC<<<dim3(64), dim3(768), 0, stream>>>(pre, Uh, Wihh, bih, gi);
    k_gru<<<dim3(1), dim3(1024), 0, stream>>>(Wq, rowscale, Whhh, bhh, gi, h0, tv,
                                              gateW, gateU, gateb, outW, outb, (float*)d_out);
}